// Round 10
// baseline (106.459 us; speedup 1.0000x reference)
//
#include <hip/hip_runtime.h>

// B=32, C=8, L=2048, K=512, S=64, W=1985
// out[b,0,q] = max(0, max_w sum_c dot(xw_n[b,c,w,:], sn_n[c,q,:]) / 8)
//
// v11: pipe-split operand feed. v10's LDS arithmetic: 24 ds_read_b32 (A) +
// 8 ds_read_b128 (B) = 235 cyc/wave/c -> 60k cyc/CU ~= 25us: LDS-bound.
// Fix: prep precomputes AX in MFMA A-frag layout (unit P = 1KB, value =
// x[P*16 + (lane&31) + (lane>>5)*8 + j]); mcs reads A as 6 coalesced
// global dwordx4 per c per wave (Hankel: frag(mt,ks) = unit P0+2mt+ks).
// B stays in the persistent 64KB LDS panel (8 ds_read_b128/c/wave).
// Per-CU pipes: MFMA 13.7us > L2 ~11 > LDS ~10 > TA ~7 -> MFMA-topped.
// NOTE: harness re-poisons the 256MiB workspace every iteration (~41us
// fill inside the timed window) -- fixed overhead, not addressable here.

#define B_ 32
#define C_ 8
#define L_ 2048
#define K_ 512
#define S_ 64
#define W_ 1985
#define NP_ 130                       // AX units per (b,c): P = 0..129

typedef _Float16 f16x8  __attribute__((ext_vector_type(8)));
typedef float    f32x16 __attribute__((ext_vector_type(16)));

// ---- prologue ----
__global__ __launch_bounds__(256)
void prep_k(const float* __restrict__ x, const float* __restrict__ sh,
            _Float16* __restrict__ Bp, float* __restrict__ invn,
            _Float16* __restrict__ AX, float* __restrict__ out) {
    __shared__ float xr[L_];
    const int tid = threadIdx.x;
    const int blk = blockIdx.x;

    if (blk < 128) {
        const int sb   = blk * 4 + (tid >> 6);   // 0..511 = c(8) x kq(4) x nt(16)
        const int c    = sb >> 6;
        const int kq   = (sb >> 4) & 3;
        const int nt   = sb & 15;
        const int lane = tid & 63;
        const int half = lane >> 5;
        const int q    = nt * 32 + (lane & 31);

        const float4* sp = (const float4*)(sh + (size_t)(c * K_ + q) * S_);
        float ss = 0.f;
        #pragma unroll
        for (int i = 0; i < 8; ++i) {
            float4 v = sp[half * 8 + i];
            ss += v.x * v.x + v.y * v.y + v.z * v.z + v.w * v.w;
        }
        ss += __shfl_xor(ss, 32);
        float inv = 1.f / fmaxf(sqrtf(ss), 1e-8f);

        float4 u0 = sp[kq * 4 + half * 2];
        float4 u1 = sp[kq * 4 + half * 2 + 1];
        f16x8 o;
        o[0] = (_Float16)(u0.x * inv); o[1] = (_Float16)(u0.y * inv);
        o[2] = (_Float16)(u0.z * inv); o[3] = (_Float16)(u0.w * inv);
        o[4] = (_Float16)(u1.x * inv); o[5] = (_Float16)(u1.y * inv);
        o[6] = (_Float16)(u1.z * inv); o[7] = (_Float16)(u1.w * inv);
        ((f16x8*)Bp)[((c * 4 + kq) * 16 + nt) * 64 + lane] = o;
    } else {
        const int r = blk - 128;                 // 0..255 = b*8+c
        const float* xp = x + (size_t)r * L_;
        for (int i = tid; i < L_ / 4; i += 256)
            ((float4*)xr)[i] = ((const float4*)xp)[i];
        __syncthreads();

        float* ivp = invn + (size_t)r * L_;
        const int w0 = tid * 8;
        float ss = 0.f;
        if (w0 < W_) {
            #pragma unroll
            for (int j = 0; j < S_; ++j) { float v = xr[w0 + j]; ss += v * v; }
        }
        #pragma unroll
        for (int u = 0; u < 8; ++u) {
            int w = w0 + u;
            float o = 0.f;
            if (u > 0 && w < W_)
                ss += xr[w + 63] * xr[w + 63] - xr[w - 1] * xr[w - 1];
            if (w < W_) o = 0.125f / fmaxf(sqrtf(ss), 1e-8f);
            if (w < L_) ivp[w] = o;
        }

        // AX: unit P value at (lane, j) = x[P*16 + (lane&31) + (lane>>5)*8 + j]
        _Float16* axp = AX + (size_t)r * (NP_ * 512);
        const int lane = tid & 63;
        const int wvp  = tid >> 6;
        const int kof  = (lane & 31) + (lane >> 5) * 8;
        #pragma unroll 1
        for (int P = wvp; P < NP_; P += 4) {
            const int base = P * 16 + kof;
            f16x8 o;
            #pragma unroll
            for (int j = 0; j < 8; ++j) {
                int e = base + j;
                o[j] = (_Float16)xr[e < L_ ? e : L_ - 1];  // tail rows have iv=0
            }
            *((f16x8*)(axp + (size_t)P * 512) + lane) = o;
        }
        if (r < 64) out[r * 256 + tid] = 0.f;    // zero output
    }
}

// global -> LDS direct copy, 16B per lane (dest = uniform base + lane*16)
__device__ __forceinline__ void glds16(const void* g, void* l) {
    __builtin_amdgcn_global_load_lds(
        (const __attribute__((address_space(1))) unsigned int*)g,
        (__attribute__((address_space(3))) unsigned int*)l, 16, 0, 0);
}

// A: 6 Hankel frag units (coalesced dwordx4) + 2 inv-norms, NAMED buffers
__device__ __forceinline__ void loadA(
    int c, const f16x8* __restrict__ axl, const float* __restrict__ ivbase,
    int m0, int m1, f16x8 (&g)[6], float (&iv)[2])
{
    iv[0] = ivbase[(size_t)c * L_ + m0];         // 0 for invalid windows
    iv[1] = ivbase[(size_t)c * L_ + m1];
    const f16x8* u = axl + (size_t)c * (NP_ * 64);
    #pragma unroll
    for (int p = 0; p < 6; ++p)
        g[p] = u[p * 64];
}

// 8 ds_read_b128 (persistent B panel) + scale A + 16 MFMAs
__device__ __forceinline__ void compC(
    int c, const f16x8* __restrict__ Bsl, int lane,
    const f16x8 (&g)[6], const float (&iv)[2], f32x16 (&acc)[2][2])
{
    f16x8 bf[8];
    #pragma unroll
    for (int ks = 0; ks < 4; ++ks)
        #pragma unroll
        for (int nt = 0; nt < 2; ++nt)
            bf[ks * 2 + nt] = Bsl[(c * 8 + ks * 2 + nt) * 64 + lane];

    const _Float16 h0 = (_Float16)iv[0], h1 = (_Float16)iv[1];
    f16x8 is0, is1;
    #pragma unroll
    for (int j = 0; j < 8; ++j) { is0[j] = h0; is1[j] = h1; }

    __builtin_amdgcn_s_setprio(1);
    #pragma unroll
    for (int ks = 0; ks < 4; ++ks) {
        f16x8 a0 = g[ks]     * is0;              // frag(mt=0,ks) = unit ks
        f16x8 a1 = g[ks + 2] * is1;              // frag(mt=1,ks) = unit ks+2
        #pragma unroll
        for (int nt = 0; nt < 2; ++nt) {
            acc[0][nt] = __builtin_amdgcn_mfma_f32_32x32x16_f16(
                a0, bf[ks * 2 + nt], acc[0][nt], 0, 0, 0);
            acc[1][nt] = __builtin_amdgcn_mfma_f32_32x32x16_f16(
                a1, bf[ks * 2 + nt], acc[1][nt], 0, 0, 0);
        }
    }
    __builtin_amdgcn_s_setprio(0);
}

// ---- main: A from pre-arranged global (coalesced), B from persistent LDS ----
// grid (8 wt, 8 ng, 32 b) = 2048 blocks, 4 waves. Wave: 64 windows (2x32)
// x 64 q (2x32); acc = 4 x f32x16 = 64. B-panel (64KB) staged once; c-loop
// barrier-free with named A double-buffers (reg prefetch one c ahead).
__global__ __launch_bounds__(256, 2)
void mcs_k(const _Float16* __restrict__ AX, const _Float16* __restrict__ Bp,
           const float* __restrict__ invn, float* __restrict__ out) {
    const int wt  = blockIdx.x;           // 0..7  256-window tile
    const int ng  = blockIdx.y;           // 0..7  64-q panel
    const int b   = blockIdx.z;
    const int tid = threadIdx.x;
    const int lane = tid & 63;
    const int wv   = tid >> 6;            // window subgroup 0..3

    const int l31 = lane & 31;
    const int Wb  = wt * 256 + wv * 64;   // wave window base
    const int m0  = Wb + l31;
    const int m1  = Wb + 32 + l31;
    const int P0  = wt * 16 + wv * 4;     // wave's AX unit base

    __shared__ __attribute__((aligned(16))) f16x8 Bs[64][64];   // 64 KB

    // ---- stage B-panel once: wave wv stages units e = wv*16..+15 ----
    {
        const f16x8* bp = (const f16x8*)Bp;
        #pragma unroll
        for (int u = 0; u < 16; ++u) {
            const int e   = wv * 16 + u;
            const int c   = e >> 3;
            const int sub = e & 7;                    // ks*2 + nt
            const int src = ((c * 4 + (sub >> 1)) * 16 + ng * 2 + (sub & 1)) * 64;
            glds16(bp + src + lane, &Bs[e][0]);
        }
    }

    const f16x8* axl = (const f16x8*)AX + ((size_t)(b * C_) * NP_ + P0) * 64 + lane;
    const float* ivbase = invn + (size_t)b * C_ * L_;

    f32x16 acc[2][2];
    #pragma unroll
    for (int mt = 0; mt < 2; ++mt)
        #pragma unroll
        for (int nt = 0; nt < 2; ++nt)
            #pragma unroll
            for (int r = 0; r < 16; ++r) acc[mt][nt][r] = 0.f;

    f16x8 gA[6], gB[6];
    float ivA[2], ivB[2];

    loadA(0, axl, ivbase, m0, m1, gA, ivA);     // overlaps the staging
    __syncthreads();                            // B-panel ready

    #pragma unroll 1
    for (int cp = 0; cp < 4; ++cp) {
        const int c0 = cp * 2;
        loadA(c0 + 1, axl, ivbase, m0, m1, gB, ivB);
        compC(c0, &Bs[0][0], lane, gA, ivA, acc);
        if (cp < 3)
            loadA(c0 + 2, axl, ivbase, m0, m1, gA, ivA);
        compC(c0 + 1, &Bs[0][0], lane, gB, ivB, acc);
    }

    // epilogue: relu + max over windows; col(q) = lane&31; fold lane^32;
    // waves cover disjoint windows -> atomicMax combines (values >= 0).
    #pragma unroll
    for (int nt = 0; nt < 2; ++nt) {
        float v = 0.f;
        #pragma unroll
        for (int mt = 0; mt < 2; ++mt)
            #pragma unroll
            for (int r = 0; r < 16; ++r) v = fmaxf(v, acc[mt][nt][r]);
        v = fmaxf(v, __shfl_xor(v, 32));
        if (lane < 32)
            atomicMax((unsigned int*)(out + (size_t)b * K_ + ng * 64 + nt * 32 + l31),
                      __float_as_uint(v));
    }
}

extern "C" void kernel_launch(void* const* d_in, const int* in_sizes, int n_in,
                              void* d_out, int out_size, void* d_ws, size_t ws_size,
                              hipStream_t stream) {
    const float* x  = (const float*)d_in[0];   // (32, 8, 2048) fp32
    const float* sh = (const float*)d_in[1];   // (8, 512, 64) fp32
    float* out = (float*)d_out;                // (32, 1, 512) fp32

    // workspace: Bp 512KB | invn 2MB | AX ~33MB (frag-layout x expansion)
    _Float16* Bp   = (_Float16*)d_ws;
    float*    invn = (float*)((char*)d_ws + (512 << 10));
    _Float16* AX   = (_Float16*)((char*)d_ws + (512 << 10) + (2 << 20));

    prep_k<<<dim3(384), dim3(256), 0, stream>>>(x, sh, Bp, invn, AX, out);
    mcs_k<<<dim3(8, 8, B_), dim3(256), 0, stream>>>(AX, Bp, invn, out);
}

// Round 11
// 99.823 us; speedup vs baseline: 1.0665x; 1.0665x over previous
//
#include <hip/hip_runtime.h>

// B=32, C=8, L=2048, K=512, S=64, W=1985
// out[b,0,q] = max(0, max_w sum_c dot(xw_n[b,c,w,:], sn_n[c,q,:]) / 8)
//
// v12: break the intra-wave pipe convoy. v5..v11 all measured ~3000-3400cy
// per c-round = TA + LDS + VALU + MFMA SUMMED (serial phases per wave,
// sibling waves in phase) regardless of feed path / schedule / occupancy.
// Fixes: (1) B-fragment ds_reads double-buffered and issued a half-iteration
// EARLY (LDB(c+1) before MFMA(c)) so LDS latency+throughput hide under the
// 512cy MFMA burst; (2) remove s_setprio brackets (they fence the scheduler
// and blocked load/MFMA interleave); (3) revert to v8 dataflow: A from xh
// global (L1 merges the overlapping gather, ~20cy/instr - v8-measured),
// B persistent 64KB LDS, no AX (fill re-poison tax ~0.2us/dirty-MB gone).

#define B_ 32
#define C_ 8
#define L_ 2048
#define K_ 512
#define S_ 64
#define W_ 1985
#define XS_ 2176                      // padded f16 row stride (L_ + 128)

typedef _Float16 f16x8  __attribute__((ext_vector_type(8)));
typedef _Float16 f16x8u __attribute__((ext_vector_type(8), aligned(4)));
typedef float    f32x16 __attribute__((ext_vector_type(16)));

// ---- prologue (v3..v9 version, harness-verified) ----
__global__ __launch_bounds__(256)
void prep_k(const float* __restrict__ x, const float* __restrict__ sh,
            _Float16* __restrict__ Bp, float* __restrict__ invn,
            _Float16* __restrict__ xh0, _Float16* __restrict__ xh1,
            float* __restrict__ out) {
    __shared__ float xr[L_];
    const int tid = threadIdx.x;
    const int blk = blockIdx.x;

    if (blk < 128) {
        const int sb   = blk * 4 + (tid >> 6);   // 0..511 = c(8) x kq(4) x nt(16)
        const int c    = sb >> 6;
        const int kq   = (sb >> 4) & 3;
        const int nt   = sb & 15;
        const int lane = tid & 63;
        const int half = lane >> 5;
        const int q    = nt * 32 + (lane & 31);

        const float4* sp = (const float4*)(sh + (size_t)(c * K_ + q) * S_);
        float ss = 0.f;
        #pragma unroll
        for (int i = 0; i < 8; ++i) {
            float4 v = sp[half * 8 + i];
            ss += v.x * v.x + v.y * v.y + v.z * v.z + v.w * v.w;
        }
        ss += __shfl_xor(ss, 32);
        float inv = 1.f / fmaxf(sqrtf(ss), 1e-8f);

        float4 u0 = sp[kq * 4 + half * 2];
        float4 u1 = sp[kq * 4 + half * 2 + 1];
        f16x8 o;
        o[0] = (_Float16)(u0.x * inv); o[1] = (_Float16)(u0.y * inv);
        o[2] = (_Float16)(u0.z * inv); o[3] = (_Float16)(u0.w * inv);
        o[4] = (_Float16)(u1.x * inv); o[5] = (_Float16)(u1.y * inv);
        o[6] = (_Float16)(u1.z * inv); o[7] = (_Float16)(u1.w * inv);
        ((f16x8*)Bp)[((c * 4 + kq) * 16 + nt) * 64 + lane] = o;
    } else {
        const int r = blk - 128;                 // 0..255 = b*8+c
        const float* xp = x + (size_t)r * L_;
        for (int i = tid; i < L_ / 4; i += 256)
            ((float4*)xr)[i] = ((const float4*)xp)[i];
        __syncthreads();

        float* ivp = invn + (size_t)r * L_;
        const int w0 = tid * 8;
        float ss = 0.f;
        if (w0 < W_) {
            #pragma unroll
            for (int j = 0; j < S_; ++j) { float v = xr[w0 + j]; ss += v * v; }
        }
        #pragma unroll
        for (int u = 0; u < 8; ++u) {
            int w = w0 + u;
            float o = 0.f;
            if (u > 0 && w < W_)
                ss += xr[w + 63] * xr[w + 63] - xr[w - 1] * xr[w - 1];
            if (w < W_) o = 0.125f / fmaxf(sqrtf(ss), 1e-8f);
            if (w < L_) ivp[w] = o;
        }

        _Float16* p0 = xh0 + (size_t)r * XS_;
        _Float16* p1 = xh1 + (size_t)r * XS_;
        for (int i = tid; i < XS_ / 8; i += 256) {
            f16x8 o0, o1;
            #pragma unroll
            for (int j = 0; j < 8; ++j) {
                int e = i * 8 + j;
                o0[j] = (_Float16)((e     < L_) ? xr[e]     : 0.f);
                o1[j] = (_Float16)((e + 1 < L_) ? xr[e + 1] : 0.f);
            }
            ((f16x8*)p0)[i] = o0;
            ((f16x8*)p1)[i] = o1;
        }
        if (r < 64) out[r * 256 + tid] = 0.f;    // zero output
    }
}

// global -> LDS direct copy, 16B per lane (dest = uniform base + lane*16)
__device__ __forceinline__ void glds16(const void* g, void* l) {
    __builtin_amdgcn_global_load_lds(
        (const __attribute__((address_space(1))) unsigned int*)g,
        (__attribute__((address_space(3))) unsigned int*)l, 16, 0, 0);
}

// A fragments + inv-norms for channel c into NAMED register buffers (10 VMEM)
__device__ __forceinline__ void loadA(
    int c, const _Float16* __restrict__ xbase, const float* __restrict__ ivbase,
    int m0, int m1, f16x8 (&ar)[8], float (&iv)[2])
{
    iv[0] = ivbase[(size_t)c * L_ + m0];         // 0 for invalid windows
    iv[1] = ivbase[(size_t)c * L_ + m1];
    const _Float16* xp = xbase + (size_t)c * XS_;
    #pragma unroll
    for (int mt = 0; mt < 2; ++mt)
        #pragma unroll
        for (int ks = 0; ks < 4; ++ks)
            ar[mt * 4 + ks] = *(const f16x8u*)(xp + mt * 32 + ks * 16);
}

// B fragments for channel c from the persistent LDS panel (8 ds_read_b128)
__device__ __forceinline__ void loadB(
    int c, const f16x8* __restrict__ Bsl, int lane, f16x8 (&bf)[8])
{
    #pragma unroll
    for (int ks = 0; ks < 4; ++ks)
        #pragma unroll
        for (int nt = 0; nt < 2; ++nt)
            bf[ks * 2 + nt] = Bsl[(c * 8 + ks * 2 + nt) * 64 + lane];
}

// scale A by per-window inv-norm + 16 MFMAs (no setprio: keep the scheduler
// free to weave the next iteration's loads into this cluster)
__device__ __forceinline__ void mfmaC(
    const f16x8 (&ar)[8], const f16x8 (&bf)[8], const float (&iv)[2],
    f32x16 (&acc)[2][2])
{
    const _Float16 h0 = (_Float16)iv[0], h1 = (_Float16)iv[1];
    f16x8 is0, is1;
    #pragma unroll
    for (int j = 0; j < 8; ++j) { is0[j] = h0; is1[j] = h1; }

    #pragma unroll
    for (int ks = 0; ks < 4; ++ks) {
        f16x8 a0 = ar[0 * 4 + ks] * is0;          // v_pk_mul_f16 x4
        f16x8 a1 = ar[1 * 4 + ks] * is1;
        #pragma unroll
        for (int nt = 0; nt < 2; ++nt) {
            acc[0][nt] = __builtin_amdgcn_mfma_f32_32x32x16_f16(
                a0, bf[ks * 2 + nt], acc[0][nt], 0, 0, 0);
            acc[1][nt] = __builtin_amdgcn_mfma_f32_32x32x16_f16(
                a1, bf[ks * 2 + nt], acc[1][nt], 0, 0, 0);
        }
    }
}

// ---- main: persistent-LDS B, fully double-buffered (A regs + B regs) ----
// grid (8 wt, 8 ng, 32 b) = 2048 blocks, 4 waves. Wave: 64 windows (2x32)
// x 64 q (2x32); acc = 4 x f32x16. Loop: LDB(c+1) issued BEFORE mfma(c) so
// the 8 ds_reads retire under the 512cy MFMA burst; loadA globals likewise
// one c ahead. Barrier-free after the single staging barrier.
__global__ __launch_bounds__(256, 2)
void mcs_k(const _Float16* __restrict__ xh0, const _Float16* __restrict__ xh1,
           const _Float16* __restrict__ Bp, const float* __restrict__ invn,
           float* __restrict__ out) {
    const int wt  = blockIdx.x;           // 0..7  256-window tile
    const int ng  = blockIdx.y;           // 0..7  64-q panel
    const int b   = blockIdx.z;
    const int tid = threadIdx.x;
    const int lane = tid & 63;
    const int wv   = tid >> 6;            // window subgroup 0..3

    const int l31 = lane & 31;
    const int lh  = lane >> 5;
    const int Wb  = wt * 256 + wv * 64;   // wave window base
    const int m0  = Wb + l31;
    const int m1  = Wb + 32 + l31;

    __shared__ __attribute__((aligned(16))) f16x8 Bs[64][64];   // 64 KB

    // ---- stage B-panel once: wave wv stages units e = wv*16..+15 ----
    {
        const f16x8* bp = (const f16x8*)Bp;
        #pragma unroll
        for (int u = 0; u < 16; ++u) {
            const int e   = wv * 16 + u;
            const int c   = e >> 3;
            const int sub = e & 7;                    // ks*2 + nt
            const int src = ((c * 4 + (sub >> 1)) * 16 + ng * 2 + (sub & 1)) * 64;
            glds16(bp + src + lane, &Bs[e][0]);
        }
    }

    // parity-selected x base keeps every f16x8 load 4B-aligned
    const _Float16* xb = (l31 & 1) ? (xh1 - 1) : xh0;
    const _Float16* xbase = xb + (size_t)b * C_ * XS_ + Wb + l31 + lh * 8;
    const float*   ivbase = invn + (size_t)b * C_ * L_;
    const f16x8*   Bsl = &Bs[0][0];

    f32x16 acc[2][2];
    #pragma unroll
    for (int mt = 0; mt < 2; ++mt)
        #pragma unroll
        for (int nt = 0; nt < 2; ++nt)
            #pragma unroll
            for (int r = 0; r < 16; ++r) acc[mt][nt][r] = 0.f;

    f16x8 aA[8], aB[8], bfA[8], bfB[8];
    float ivA[2], ivB[2];

    loadA(0, xbase, ivbase, m0, m1, aA, ivA);   // overlaps the staging
    loadA(1, xbase, ivbase, m0, m1, aB, ivB);
    __syncthreads();                            // B-panel ready
    loadB(0, Bsl, lane, bfA);                   // prime the LDS pipeline

    #pragma unroll 1
    for (int cp = 0; cp < 4; ++cp) {
        const int c0 = cp * 2;
        loadB(c0 + 1, Bsl, lane, bfB);          // in flight under mfma(c0)
        mfmaC(aA, bfA, ivA, acc);               // c0
        if (cp < 3) {
            loadA(c0 + 2, xbase, ivbase, m0, m1, aA, ivA);
            loadB(c0 + 2, Bsl, lane, bfA);      // in flight under mfma(c0+1)
        }
        mfmaC(aB, bfB, ivB, acc);               // c0+1
        if (cp < 3)
            loadA(c0 + 3, xbase, ivbase, m0, m1, aB, ivB);
    }

    // epilogue: relu + max over windows; col(q) = lane&31; fold lane^32;
    // waves cover disjoint windows -> atomicMax combines (values >= 0).
    #pragma unroll
    for (int nt = 0; nt < 2; ++nt) {
        float v = 0.f;
        #pragma unroll
        for (int mt = 0; mt < 2; ++mt)
            #pragma unroll
            for (int r = 0; r < 16; ++r) v = fmaxf(v, acc[mt][nt][r]);
        v = fmaxf(v, __shfl_xor(v, 32));
        if (lane < 32)
            atomicMax((unsigned int*)(out + (size_t)b * K_ + ng * 64 + nt * 32 + l31),
                      __float_as_uint(v));
    }
}

extern "C" void kernel_launch(void* const* d_in, const int* in_sizes, int n_in,
                              void* d_out, int out_size, void* d_ws, size_t ws_size,
                              hipStream_t stream) {
    const float* x  = (const float*)d_in[0];   // (32, 8, 2048) fp32
    const float* sh = (const float*)d_in[1];   // (8, 512, 64) fp32
    float* out = (float*)d_out;                // (32, 1, 512) fp32

    // workspace: Bp 512KB | invn 2MB | xh0 ~1.06MB | xh1 ~1.06MB (~4.7MB
    // dirty footprint -- keeps the harness's 256MiB re-poison fill fast)
    _Float16* Bp   = (_Float16*)d_ws;
    float*    invn = (float*)((char*)d_ws + (512 << 10));
    _Float16* xh0  = (_Float16*)((char*)d_ws + (512 << 10) + (2 << 20));
    _Float16* xh1  = xh0 + (size_t)B_ * C_ * XS_;

    prep_k<<<dim3(384), dim3(256), 0, stream>>>(x, sh, Bp, invn, xh0, xh1, out);
    mcs_k<<<dim3(8, 8, B_), dim3(256), 0, stream>>>(xh0, xh1, Bp, invn, out);
}

// Round 12
// 94.736 us; speedup vs baseline: 1.1237x; 1.0537x over previous
//
#include <hip/hip_runtime.h>

// B=32, C=8, L=2048, K=512, S=64, W=1985
// out[b,0,q] = max(0, max_w sum_c dot(xw_n[b,c,w,:], sn_n[c,q,:]) / 8)
//
// v13: raise MFMA-per-feed-instruction. v5..v12 all measured ~3,600cy per
// c-round per CU =~ 80 wave64 VMEM instrs x ~40cy TA cost -- feed-instr
// bound, invariant to path/schedule/occupancy. v13 changes the RATIO:
//  (a) block covers 128 q (ng 8->4): halves the ng-duplication of the
//      A-gather; 64KB B-panel re-staged once mid-kernel (2 phases x 4 c).
//  (b) Hankel dedup: af[1][0]==af[0][2], af[1][1]==af[0][3] -> 6 raw A
//      loads (not 8) + 2 iv = 8 VMEM feeding 32 MFMAs (v12: 10 per 16).
// Per-CU TA instrs 2560 -> ~1540; MFMA per c-round per SIMD 1024 -> 2048.

#define B_ 32
#define C_ 8
#define L_ 2048
#define K_ 512
#define S_ 64
#define W_ 1985
#define XS_ 2176                      // padded f16 row stride (L_ + 128)

typedef _Float16 f16x8  __attribute__((ext_vector_type(8)));
typedef _Float16 f16x8u __attribute__((ext_vector_type(8), aligned(4)));
typedef float    f32x16 __attribute__((ext_vector_type(16)));

// ---- prologue (v3..v12 version, harness-verified) ----
__global__ __launch_bounds__(256)
void prep_k(const float* __restrict__ x, const float* __restrict__ sh,
            _Float16* __restrict__ Bp, float* __restrict__ invn,
            _Float16* __restrict__ xh0, _Float16* __restrict__ xh1,
            float* __restrict__ out) {
    __shared__ float xr[L_];
    const int tid = threadIdx.x;
    const int blk = blockIdx.x;

    if (blk < 128) {
        const int sb   = blk * 4 + (tid >> 6);   // 0..511 = c(8) x kq(4) x nt(16)
        const int c    = sb >> 6;
        const int kq   = (sb >> 4) & 3;
        const int nt   = sb & 15;
        const int lane = tid & 63;
        const int half = lane >> 5;
        const int q    = nt * 32 + (lane & 31);

        const float4* sp = (const float4*)(sh + (size_t)(c * K_ + q) * S_);
        float ss = 0.f;
        #pragma unroll
        for (int i = 0; i < 8; ++i) {
            float4 v = sp[half * 8 + i];
            ss += v.x * v.x + v.y * v.y + v.z * v.z + v.w * v.w;
        }
        ss += __shfl_xor(ss, 32);
        float inv = 1.f / fmaxf(sqrtf(ss), 1e-8f);

        float4 u0 = sp[kq * 4 + half * 2];
        float4 u1 = sp[kq * 4 + half * 2 + 1];
        f16x8 o;
        o[0] = (_Float16)(u0.x * inv); o[1] = (_Float16)(u0.y * inv);
        o[2] = (_Float16)(u0.z * inv); o[3] = (_Float16)(u0.w * inv);
        o[4] = (_Float16)(u1.x * inv); o[5] = (_Float16)(u1.y * inv);
        o[6] = (_Float16)(u1.z * inv); o[7] = (_Float16)(u1.w * inv);
        ((f16x8*)Bp)[((c * 4 + kq) * 16 + nt) * 64 + lane] = o;
    } else {
        const int r = blk - 128;                 // 0..255 = b*8+c
        const float* xp = x + (size_t)r * L_;
        for (int i = tid; i < L_ / 4; i += 256)
            ((float4*)xr)[i] = ((const float4*)xp)[i];
        __syncthreads();

        float* ivp = invn + (size_t)r * L_;
        const int w0 = tid * 8;
        float ss = 0.f;
        if (w0 < W_) {
            #pragma unroll
            for (int j = 0; j < S_; ++j) { float v = xr[w0 + j]; ss += v * v; }
        }
        #pragma unroll
        for (int u = 0; u < 8; ++u) {
            int w = w0 + u;
            float o = 0.f;
            if (u > 0 && w < W_)
                ss += xr[w + 63] * xr[w + 63] - xr[w - 1] * xr[w - 1];
            if (w < W_) o = 0.125f / fmaxf(sqrtf(ss), 1e-8f);
            if (w < L_) ivp[w] = o;
        }

        _Float16* p0 = xh0 + (size_t)r * XS_;
        _Float16* p1 = xh1 + (size_t)r * XS_;
        for (int i = tid; i < XS_ / 8; i += 256) {
            f16x8 o0, o1;
            #pragma unroll
            for (int j = 0; j < 8; ++j) {
                int e = i * 8 + j;
                o0[j] = (_Float16)((e     < L_) ? xr[e]     : 0.f);
                o1[j] = (_Float16)((e + 1 < L_) ? xr[e + 1] : 0.f);
            }
            ((f16x8*)p0)[i] = o0;
            ((f16x8*)p1)[i] = o1;
        }
        if (r < 64) out[r * 256 + tid] = 0.f;    // zero output
    }
}

// global -> LDS direct copy, 16B per lane (dest = uniform base + lane*16)
__device__ __forceinline__ void glds16(const void* g, void* l) {
    __builtin_amdgcn_global_load_lds(
        (const __attribute__((address_space(1))) unsigned int*)g,
        (__attribute__((address_space(3))) unsigned int*)l, 16, 0, 0);
}

// A: 6 distinct Hankel fragments (raw, unscaled) + 2 inv-norms (8 VMEM).
// raw[p] covers k-offset p*16; frag(mt,ks) = raw[mt*2 + ks].
__device__ __forceinline__ void loadA(
    int c, const _Float16* __restrict__ xbase, const float* __restrict__ ivbase,
    int m0, int m1, f16x8 (&g)[6], float (&iv)[2])
{
    iv[0] = ivbase[(size_t)c * L_ + m0];         // 0 for invalid windows
    iv[1] = ivbase[(size_t)c * L_ + m1];
    const _Float16* xp = xbase + (size_t)c * XS_;
    #pragma unroll
    for (int p = 0; p < 6; ++p)
        g[p] = *(const f16x8u*)(xp + p * 16);
}

// one channel: 16 ds_read_b128 (each B frag consumed immediately by an
// (a0,a1) MFMA pair -> ~2 live bf regs) + 32 MFMAs. cc = c & 3.
__device__ __forceinline__ void compC(
    int cc, const f16x8* __restrict__ Bsl, int lane,
    const f16x8 (&g)[6], const float (&iv)[2], f32x16 (&acc)[2][4])
{
    const _Float16 h0 = (_Float16)iv[0], h1 = (_Float16)iv[1];
    f16x8 is0, is1;
    #pragma unroll
    for (int j = 0; j < 8; ++j) { is0[j] = h0; is1[j] = h1; }

    #pragma unroll
    for (int ks = 0; ks < 4; ++ks) {
        f16x8 a0 = g[ks]     * is0;              // frag(mt=0,ks) = raw[ks]
        f16x8 a1 = g[ks + 2] * is1;              // frag(mt=1,ks) = raw[ks+2]
        #pragma unroll
        for (int nt = 0; nt < 4; ++nt) {
            f16x8 bf = Bsl[((cc * 4 + ks) * 4 + nt) * 64 + lane];
            acc[0][nt] = __builtin_amdgcn_mfma_f32_32x32x16_f16(
                a0, bf, acc[0][nt], 0, 0, 0);
            acc[1][nt] = __builtin_amdgcn_mfma_f32_32x32x16_f16(
                a1, bf, acc[1][nt], 0, 0, 0);
        }
    }
}

// ---- main: 2-phase persistent-LDS B (4 c x 128 q per phase) ----
// grid (8 wt, 4 ng, 32 b) = 1024 blocks, 4 waves. Wave: 64 windows (2x32)
// x 128 q (4x32); acc = 8 x f32x16 = 128 regs. Phase p: stage 64KB B-panel
// for c = p*4..p*4+3 (16 glds16/wave), barrier, then 4 barrier-free c-steps
// with A reg-prefetch (6 Hankel frags + 2 iv = 8 VMEM per 32 MFMAs).
__global__ __launch_bounds__(256, 2)
void mcs_k(const _Float16* __restrict__ xh0, const _Float16* __restrict__ xh1,
           const _Float16* __restrict__ Bp, const float* __restrict__ invn,
           float* __restrict__ out) {
    const int wt  = blockIdx.x;           // 0..7  256-window tile
    const int ng  = blockIdx.y;           // 0..3  128-q panel
    const int b   = blockIdx.z;
    const int tid = threadIdx.x;
    const int lane = tid & 63;
    const int wv   = tid >> 6;            // window subgroup 0..3

    const int l31 = lane & 31;
    const int lh  = lane >> 5;
    const int Wb  = wt * 256 + wv * 64;   // wave window base
    const int m0  = Wb + l31;
    const int m1  = Wb + 32 + l31;

    __shared__ __attribute__((aligned(16))) f16x8 Bs[64][64];   // 64 KB/phase

    // parity-selected x base keeps every f16x8 load 4B-aligned
    const _Float16* xb = (l31 & 1) ? (xh1 - 1) : xh0;
    const _Float16* xbase = xb + (size_t)b * C_ * XS_ + Wb + l31 + lh * 8;
    const float*   ivbase = invn + (size_t)b * C_ * L_;
    const f16x8*   Bsl = &Bs[0][0];
    const f16x8*   bp  = (const f16x8*)Bp;

    f32x16 acc[2][4];
    #pragma unroll
    for (int mt = 0; mt < 2; ++mt)
        #pragma unroll
        for (int nt = 0; nt < 4; ++nt)
            #pragma unroll
            for (int r = 0; r < 16; ++r) acc[mt][nt][r] = 0.f;

    f16x8 gE[6], gO[6];
    float ivE[2], ivO[2];

    // stage phase p's B-panel: unit e = cc*16 + ks*4 + nt  (cc = c&3)
    #define STAGE(p)                                                    \
        { _Pragma("unroll")                                             \
          for (int u = 0; u < 16; ++u) {                                \
              const int e  = wv * 16 + u;                               \
              const int cc = e >> 4, ks = (e >> 2) & 3, nt = e & 3;     \
              const int src = ((((p) * 4 + cc) * 4 + ks) * 16           \
                               + ng * 4 + nt) * 64;                     \
              glds16(bp + src + lane, &Bs[e][0]);                       \
          } }

    #pragma unroll 1
    for (int p = 0; p < 2; ++p) {
        const int c0 = p * 4;
        if (p) __syncthreads();           // all waves done reading phase 0
        STAGE(p);
        loadA(c0 + 0, xbase, ivbase, m0, m1, gE, ivE);
        loadA(c0 + 1, xbase, ivbase, m0, m1, gO, ivO);
        __syncthreads();                  // panel ready (vmcnt drained)

        compC(0, Bsl, lane, gE, ivE, acc);
        loadA(c0 + 2, xbase, ivbase, m0, m1, gE, ivE);
        compC(1, Bsl, lane, gO, ivO, acc);
        loadA(c0 + 3, xbase, ivbase, m0, m1, gO, ivO);
        compC(2, Bsl, lane, gE, ivE, acc);
        compC(3, Bsl, lane, gO, ivO, acc);
    }
    #undef STAGE

    // epilogue: relu + max over windows; C/D col(q) = lane&31, rows =
    // windows; fold lane^32 (same q), waves cover disjoint windows ->
    // atomicMax combines (values >= 0, uint compare valid).
    #pragma unroll
    for (int nt = 0; nt < 4; ++nt) {
        float v = 0.f;
        #pragma unroll
        for (int mt = 0; mt < 2; ++mt)
            #pragma unroll
            for (int r = 0; r < 16; ++r) v = fmaxf(v, acc[mt][nt][r]);
        v = fmaxf(v, __shfl_xor(v, 32));
        if (lane < 32)
            atomicMax((unsigned int*)(out + (size_t)b * K_ + ng * 128 + nt * 32 + l31),
                      __float_as_uint(v));
    }
}

extern "C" void kernel_launch(void* const* d_in, const int* in_sizes, int n_in,
                              void* d_out, int out_size, void* d_ws, size_t ws_size,
                              hipStream_t stream) {
    const float* x  = (const float*)d_in[0];   // (32, 8, 2048) fp32
    const float* sh = (const float*)d_in[1];   // (8, 512, 64) fp32
    float* out = (float*)d_out;                // (32, 1, 512) fp32

    // workspace: Bp 512KB | invn 2MB | xh0 ~1.06MB | xh1 ~1.06MB (~4.7MB
    // dirty footprint -- keeps the harness's 256MiB re-poison fill fast)
    _Float16* Bp   = (_Float16*)d_ws;
    float*    invn = (float*)((char*)d_ws + (512 << 10));
    _Float16* xh0  = (_Float16*)((char*)d_ws + (512 << 10) + (2 << 20));
    _Float16* xh1  = xh0 + (size_t)B_ * C_ * XS_;

    prep_k<<<dim3(384), dim3(256), 0, stream>>>(x, sh, Bp, invn, xh0, xh1, out);
    mcs_k<<<dim3(8, 4, B_), dim3(256), 0, stream>>>(xh0, xh1, Bp, invn, out);
}